// Round 6
// baseline (1080.110 us; speedup 1.0000x reference)
//
#include <hip/hip_runtime.h>
#include <math.h>

#define N_NODES 100000
#define N_EDGES 3200000
#define DIM_IN 128
#define HL 32
#define DIM_OUT 40
#define BN_EPS 1e-5f

#define NBUCKET 1563            // ceil(100000/64): 64-node buckets (dst>>6)
#define NBH 256                 // bhist blocks; 256*12500 == N_EDGES exactly

// ---------------- Wc = W @ c1_W1  (128x128 @ 128x32) ----------------
__global__ __launch_bounds__(256) void k_wc(const float* __restrict__ W,
                                            const float* __restrict__ W1,
                                            float* __restrict__ Wc) {
    int idx = blockIdx.x * 256 + threadIdx.x;   // 0..4095
    int i = idx >> 5;   // 0..127
    int j = idx & 31;   // 0..31
    float acc = 0.f;
    for (int k = 0; k < DIM_IN; ++k) acc += W[i * DIM_IN + k] * W1[k * HL + j];
    Wc[i * HL + j] = acc;
}

// ---------------- u = x @ Wc  ([N,128] @ [128,32]), 64 nodes/block ----------------
__global__ __launch_bounds__(256) void k_xproj(const float* __restrict__ x,
                                               const float* __restrict__ Wc,
                                               float* __restrict__ u) {
    __shared__ float xs[64][132];     // padded: row stride 132 -> bank shift 4
    __shared__ float Ws[DIM_IN * HL]; // 16 KB
    int t = threadIdx.x;
    int base = blockIdx.x * 64;
    for (int i = t; i < DIM_IN * HL / 4; i += 256)
        ((float4*)Ws)[i] = ((const float4*)Wc)[i];
    for (int i = t; i < 64 * 32; i += 256) {     // 2048 float4s
        int r = i >> 5, c4 = i & 31;
        float4 val;
        if (base + r < N_NODES) val = ((const float4*)x)[(size_t)(base + r) * 32 + c4];
        else val = make_float4(0.f, 0.f, 0.f, 0.f);
        *(float4*)&xs[r][c4 * 4] = val;
    }
    __syncthreads();
    int mg = t >> 3;      // 0..31 -> nodes 2mg, 2mg+1
    int cg = t & 7;       // cols cg*4..+3
    int n0 = mg * 2;
    float4 a0 = make_float4(0.f, 0.f, 0.f, 0.f);
    float4 a1 = make_float4(0.f, 0.f, 0.f, 0.f);
    for (int k = 0; k < DIM_IN; ++k) {
        float x0 = xs[n0][k], x1 = xs[n0 + 1][k];
        float4 b = ((float4*)Ws)[k * 8 + cg];
        a0.x += x0 * b.x; a0.y += x0 * b.y; a0.z += x0 * b.z; a0.w += x0 * b.w;
        a1.x += x1 * b.x; a1.y += x1 * b.y; a1.z += x1 * b.z; a1.w += x1 * b.w;
    }
    int node = base + n0;
    if (node < N_NODES)     ((float4*)u)[(size_t)node * 8 + cg] = a0;
    if (node + 1 < N_NODES) ((float4*)u)[(size_t)(node + 1) * 8 + cg] = a1;
}

// ---------------- bucket histogram (LDS-local, merged once) ----------------
__global__ __launch_bounds__(256) void k_bhist(const int* __restrict__ dst,
                                               int* __restrict__ bhist) {
    __shared__ int bins[NBUCKET];
    int t = threadIdx.x;
    for (int i = t; i < NBUCKET; i += 256) bins[i] = 0;
    __syncthreads();
    int e0 = blockIdx.x * (N_EDGES / NBH);
    int e1 = e0 + (N_EDGES / NBH);
    for (int e = e0 + t; e < e1; e += 256) atomicAdd(&bins[dst[e] >> 6], 1);
    __syncthreads();
    for (int i = t; i < NBUCKET; i += 256) {
        int v = bins[i];
        if (v) atomicAdd(&bhist[i], v);
    }
}

// ---------------- generic scan pieces (used for the 1563-entry bucket scan) ----------------
__global__ __launch_bounds__(256) void k_scan1(const int* __restrict__ in,
                                               int* __restrict__ outp,
                                               int* __restrict__ bsums, int n) {
    __shared__ int s[256];
    int t = threadIdx.x;
    int i = blockIdx.x * 256 + t;
    int val = (i < n) ? in[i] : 0;
    s[t] = val;
    __syncthreads();
    for (int off = 1; off < 256; off <<= 1) {
        int a = 0;
        if (t >= off) a = s[t - off];
        __syncthreads();
        s[t] += a;
        __syncthreads();
    }
    if (i < n) outp[i] = s[t] - val;   // exclusive within block
    if (t == 255) bsums[blockIdx.x] = s[255];
}

__global__ __launch_bounds__(512) void k_scan2(const int* __restrict__ bsums,
                                               int* __restrict__ boffs, int nb) {
    __shared__ int s[512];
    int t = threadIdx.x;
    int val = (t < nb) ? bsums[t] : 0;
    s[t] = val;
    __syncthreads();
    for (int off = 1; off < 512; off <<= 1) {
        int a = 0;
        if (t >= off) a = s[t - off];
        __syncthreads();
        s[t] += a;
        __syncthreads();
    }
    if (t < nb) boffs[t] = s[t] - val;
}

__global__ void k_scan3(int* __restrict__ arr, const int* __restrict__ boffs,
                        int n, int total, int write_total) {
    int i = blockIdx.x * 256 + threadIdx.x;
    if (i < n) arr[i] += boffs[i >> 8];
    if (write_total && i == 0) arr[n] = total;
}

// ---- bucket scatter: global atomic cursors on 1563 buckets, full-occupancy grid ----
// gcur[b] holds the bucket's exclusive base on entry; on exit gcur[b] == bucket end.
__global__ __launch_bounds__(256) void k_scatA(const int* __restrict__ src,
                                               const int* __restrict__ dst,
                                               int* __restrict__ gcur,
                                               unsigned int* __restrict__ pairs) {
    int e = blockIdx.x * 256 + threadIdx.x;   // 12500*256 == N_EDGES exactly
    int d = dst[e];
    int p = atomicAdd(&gcur[d >> 6], 1);
    pairs[p] = ((unsigned int)src[e] << 6) | (unsigned int)(d & 63);
}

// ---- per-bucket: build row_ptr (64-bin hist + wave scan) and node-order srcs ----
__global__ __launch_bounds__(256) void k_scatB(const unsigned int* __restrict__ pairs,
                                               const int* __restrict__ gcur,
                                               int* __restrict__ row_ptr,
                                               int* __restrict__ srcs) {
    __shared__ int bins[64];
    __shared__ int cur[64];
    int t = threadIdx.x, b = blockIdx.x;
    int base = (b == 0) ? 0 : gcur[b - 1];   // post-scatA: gcur[b-1] == base of b
    int end  = gcur[b];
    if (t < 64) bins[t] = 0;
    __syncthreads();
    for (int i = base + t; i < end; i += 256) atomicAdd(&bins[pairs[i] & 63u], 1);
    __syncthreads();
    if (t < 64) {                       // wave-0 exclusive scan of 64 bins
        int v = bins[t];
        int inc = v;
        for (int off = 1; off < 64; off <<= 1) {
            int o = __shfl_up(inc, off, 64);
            if (t >= off) inc += o;
        }
        int pos = base + inc - v;
        cur[t] = pos;
        int node = (b << 6) + t;
        if (node < N_NODES) row_ptr[node] = pos;
    }
    if (b == NBUCKET - 1 && t == 0) row_ptr[N_NODES] = N_EDGES;
    __syncthreads();
    for (int i = base + t; i < end; i += 256) {
        unsigned int v = pairs[i];
        int p = atomicAdd(&cur[v & 63u], 1);
        srcs[p] = (int)(v >> 6);
    }
}

// ---- fused conv: compact-u gather + BN + ReLU + @W2 + b2 + ReLU -> hcat slice ----
// Also emits u_next = h @ W1n (pre-projection for the NEXT conv) when W1n != nullptr.
__global__ __launch_bounds__(256) void k_conv(const float* __restrict__ u,
                                              const int* __restrict__ row_ptr,
                                              const int* __restrict__ srcs,
                                              const float* __restrict__ b1,
                                              const float* __restrict__ g,
                                              const float* __restrict__ be,
                                              const float* __restrict__ m,
                                              const float* __restrict__ v,
                                              const float* __restrict__ W2,
                                              const float* __restrict__ b2,
                                              const float* __restrict__ W1n,
                                              float* __restrict__ hout,   // hcat + col_off
                                              float* __restrict__ unext) {
    __shared__ float W2s[HL * HL];
    __shared__ float W1ns[HL * HL];
    __shared__ float ts[8][HL + 1];
    __shared__ float hs[8][HL + 1];
    int t = threadIdx.x;
    bool hasN = (W1n != nullptr);
    for (int i = t; i < HL * HL; i += 256) {
        W2s[i] = W2[i];
        if (hasN) W1ns[i] = W1n[i];
    }
    int slot = t >> 5, d = t & 31;
    int node = blockIdx.x * 8 + slot;          // 12500*8 == N_NODES exactly
    float A = u[(size_t)node * HL + d];
    int e0 = row_ptr[node], e1 = row_ptr[node + 1];
    for (int base = e0; base < e1; base += 32) {
        int p = base + d;
        int idx = srcs[p < e1 ? p : e1 - 1];
        int cnt = e1 - base; if (cnt > 32) cnt = 32;
        float a0 = 0.f, a1 = 0.f, a2 = 0.f, a3 = 0.f;
        int j = 0;
        for (; j + 4 <= cnt; j += 4) {
            int s0 = __shfl(idx, j + 0, 32);
            int s1 = __shfl(idx, j + 1, 32);
            int s2 = __shfl(idx, j + 2, 32);
            int s3 = __shfl(idx, j + 3, 32);
            a0 += u[(size_t)s0 * HL + d];
            a1 += u[(size_t)s1 * HL + d];
            a2 += u[(size_t)s2 * HL + d];
            a3 += u[(size_t)s3 * HL + d];
        }
        for (; j < cnt; ++j) a0 += u[(size_t)__shfl(idx, j, 32) * HL + d];
        A += (a0 + a1) + (a2 + a3);
    }
    // folded BN affine on (A + b1)
    float s = g[d] * rsqrtf(v[d] + BN_EPS);
    float beta = (b1[d] - m[d]) * s + be[d];
    ts[slot][d] = fmaxf(A * s + beta, 0.f);
    __syncthreads();
    float h = b2[d];
    #pragma unroll
    for (int k = 0; k < HL; ++k) h += ts[slot][k] * W2s[k * HL + d];
    h = fmaxf(h, 0.f);
    hout[(size_t)node * DIM_IN + d] = h;
    if (hasN) {
        hs[slot][d] = h;
        __syncthreads();
        float un = 0.f;
        #pragma unroll
        for (int k = 0; k < HL; ++k) un += hs[slot][k] * W1ns[k * HL + d];
        unext[(size_t)node * HL + d] = un;
    }
}

// ------- final: lin1 + ReLU + lin2 + log_softmax, 32 nodes/block, 4x4 acc -------
__global__ __launch_bounds__(256, 4) void k_final(const float* __restrict__ hcat,
                                                  const float* __restrict__ W1,
                                                  const float* __restrict__ b1,
                                                  const float* __restrict__ W2,
                                                  const float* __restrict__ b2,
                                                  float* __restrict__ out) {
    __shared__ float sh_h[32][132];   // row stride 132 -> bank shift 4
    __shared__ float shW[5120];       // W1 32-row chunk (4096 floats) / W2 full (5120)
    int t = threadIdx.x;
    int base = blockIdx.x * 32;       // 3125 * 32 == 100000 exactly
    for (int i = t; i < 1024; i += 256) {
        int r = i >> 5, c4 = i & 31;
        *(float4*)&sh_h[r][c4 * 4] =
            ((const float4*)hcat)[(size_t)(base + r) * 32 + c4];
    }
    int cg = t & 31;          // col group: cols c0..c0+3
    int ng = t >> 5;          // node group: nodes n0..n0+3
    int c0 = cg * 4, n0 = ng * 4;
    float acc[4][4];
    float4 bias = ((const float4*)b1)[cg];
    #pragma unroll
    for (int i = 0; i < 4; ++i) {
        acc[i][0] = bias.x; acc[i][1] = bias.y; acc[i][2] = bias.z; acc[i][3] = bias.w;
    }
    for (int kk = 0; kk < DIM_IN; kk += 32) {
        __syncthreads();
        for (int i = t; i < 1024; i += 256)
            ((float4*)shW)[i] = ((const float4*)W1)[(size_t)(kk + (i >> 5)) * 32 + (i & 31)];
        __syncthreads();
        #pragma unroll 4
        for (int k = 0; k < 32; ++k) {
            float4 b = ((float4*)shW)[k * 32 + cg];
            #pragma unroll
            for (int i = 0; i < 4; ++i) {
                float a = sh_h[n0 + i][kk + k];
                acc[i][0] += a * b.x; acc[i][1] += a * b.y;
                acc[i][2] += a * b.z; acc[i][3] += a * b.w;
            }
        }
    }
    __syncthreads();
    #pragma unroll
    for (int i = 0; i < 4; ++i) {
        float4 vv = make_float4(fmaxf(acc[i][0], 0.f), fmaxf(acc[i][1], 0.f),
                                fmaxf(acc[i][2], 0.f), fmaxf(acc[i][3], 0.f));
        *(float4*)&sh_h[n0 + i][c0] = vv;
    }
    for (int i = t; i < 1280; i += 256) ((float4*)shW)[i] = ((const float4*)W2)[i];
    __syncthreads();
    int nn = t >> 3;
    int c2 = (t & 7) * 5;
    float acc2[5];
    #pragma unroll
    for (int j = 0; j < 5; ++j) acc2[j] = b2[c2 + j];
    #pragma unroll 4
    for (int k = 0; k < DIM_IN; ++k) {
        float a = sh_h[nn][k];
        #pragma unroll
        for (int j = 0; j < 5; ++j) acc2[j] += a * shW[k * 40 + c2 + j];
    }
    float mx = acc2[0];
    #pragma unroll
    for (int j = 1; j < 5; ++j) mx = fmaxf(mx, acc2[j]);
    for (int off = 1; off < 8; off <<= 1) mx = fmaxf(mx, __shfl_xor(mx, off, 8));
    float sm = 0.f;
    #pragma unroll
    for (int j = 0; j < 5; ++j) sm += expf(acc2[j] - mx);
    for (int off = 1; off < 8; off <<= 1) sm += __shfl_xor(sm, off, 8);
    float lz = mx + logf(sm);
    int node = base + nn;
    #pragma unroll
    for (int j = 0; j < 5; ++j) {
        float o = acc2[j];
        out[(size_t)node * DIM_OUT + c2 + j] = o;
        out[(size_t)N_NODES * DIM_OUT + (size_t)node * DIM_OUT + c2 + j] = o - lz;
    }
}

extern "C" void kernel_launch(void* const* d_in, const int* in_sizes, int n_in,
                              void* d_out, int out_size, void* d_ws, size_t ws_size,
                              hipStream_t stream) {
    const float* x      = (const float*)d_in[0];
    const int*   ei     = (const int*)d_in[1];
    const float* W      = (const float*)d_in[2];
    const float* c1_W1  = (const float*)d_in[3];
    const float* c1_b1  = (const float*)d_in[4];
    const float* c1_g   = (const float*)d_in[5];
    const float* c1_be  = (const float*)d_in[6];
    const float* c1_m   = (const float*)d_in[7];
    const float* c1_v   = (const float*)d_in[8];
    const float* c1_W2  = (const float*)d_in[9];
    const float* c1_b2  = (const float*)d_in[10];
    const float* cW1    = (const float*)d_in[11];
    const float* cb1    = (const float*)d_in[12];
    const float* cg     = (const float*)d_in[13];
    const float* cbe    = (const float*)d_in[14];
    const float* cm     = (const float*)d_in[15];
    const float* cv     = (const float*)d_in[16];
    const float* cW2    = (const float*)d_in[17];
    const float* cb2    = (const float*)d_in[18];
    const float* lin1_W = (const float*)d_in[19];
    const float* lin1_b = (const float*)d_in[20];
    const float* lin2_W = (const float*)d_in[21];
    const float* lin2_b = (const float*)d_in[22];

    const int* esrc = ei;
    const int* edst = ei + N_EDGES;

    // workspace carve (~77.2 MB)
    float* uA      = (float*)d_ws;                       // N*32 floats
    float* hcat    = uA + (size_t)N_NODES * HL;          // N*128 floats
    unsigned int* pairs = (unsigned int*)hcat;           // alias: used before hcat is written
    float* Wc      = hcat + (size_t)N_NODES * DIM_IN;    // 128*32
    int*   row_ptr = (int*)(Wc + DIM_IN * HL);           // N+1
    int*   bhist   = row_ptr + (N_NODES + 1);            // NBUCKET
    int*   gcur    = bhist + NBUCKET;                    // NBUCKET+1
    int*   srcs    = gcur + (NBUCKET + 1);               // E
    int*   bsums   = srcs + N_EDGES;                     // 512
    int*   boffs   = bsums + 512;                        // 512

    float* uB = (float*)d_out;   // scratch until k_final rewrites d_out (12.8 of 32 MB)

    const int NB_EDGE = N_EDGES / 256;           // 12500 (exact)
    const int NB_CONV = N_NODES / 8;             // 12500 (exact)
    const int NB_T64  = (N_NODES + 63) / 64;     // 1563
    const int NB_BKT  = (NBUCKET + 255) / 256;   // 7

    hipMemsetAsync(bhist, 0, NBUCKET * sizeof(int), stream);
    k_wc<<<16, 256, 0, stream>>>(W, c1_W1, Wc);
    k_xproj<<<NB_T64, 256, 0, stream>>>(x, Wc, uA);

    // bucket CSR: hist -> scan -> atomic-cursor scatter -> per-bucket node order
    k_bhist<<<NBH, 256, 0, stream>>>(edst, bhist);
    k_scan1<<<NB_BKT, 256, 0, stream>>>(bhist, gcur, bsums, NBUCKET);
    k_scan2<<<1, 512, 0, stream>>>(bsums, boffs, NB_BKT);
    k_scan3<<<NB_BKT, 256, 0, stream>>>(gcur, boffs, NBUCKET, N_EDGES, 1);
    k_scatA<<<NB_EDGE, 256, 0, stream>>>(esrc, edst, gcur, pairs);
    k_scatB<<<NBUCKET, 256, 0, stream>>>(pairs, gcur, row_ptr, srcs);

    // conv1..4: gather compact u, emit next conv's pre-projected u (ping-pong uA/uB)
    k_conv<<<NB_CONV, 256, 0, stream>>>(uA, row_ptr, srcs, c1_b1, c1_g, c1_be, c1_m,
                                        c1_v, c1_W2, c1_b2, cW1, hcat, uB);
    k_conv<<<NB_CONV, 256, 0, stream>>>(uB, row_ptr, srcs, cb1, cg, cbe, cm, cv,
                                        cW2, cb2, cW1 + HL * HL, hcat + HL, uA);
    k_conv<<<NB_CONV, 256, 0, stream>>>(uA, row_ptr, srcs, cb1 + HL, cg + HL, cbe + HL,
                                        cm + HL, cv + HL, cW2 + HL * HL, cb2 + HL,
                                        cW1 + 2 * HL * HL, hcat + 2 * HL, uB);
    k_conv<<<NB_CONV, 256, 0, stream>>>(uB, row_ptr, srcs, cb1 + 2 * HL, cg + 2 * HL,
                                        cbe + 2 * HL, cm + 2 * HL, cv + 2 * HL,
                                        cW2 + 2 * HL * HL, cb2 + 2 * HL,
                                        nullptr, hcat + 3 * HL, nullptr);

    k_final<<<N_NODES / 32, 256, 0, stream>>>(hcat, lin1_W, lin1_b, lin2_W, lin2_b,
                                              (float*)d_out);
}

// Round 7
// 705.845 us; speedup vs baseline: 1.5302x; 1.5302x over previous
//
#include <hip/hip_runtime.h>
#include <math.h>

#define N_NODES 100000
#define N_EDGES 3200000
#define DIM_IN 128
#define HL 32
#define DIM_OUT 40
#define BN_EPS 1e-5f

#define NBUCKET 1563            // fine buckets: dst>>6 (64 nodes)
#define NC 196                  // coarse buckets: dst>>9 (512 nodes)
#define NBLKA 1024              // partition blocks; 1024*3125 == N_EDGES exactly
#define TILEA 3125
#define M_CNT (NC * NBLKA)      // 200704 coarse count-matrix entries

// ---------------- Wc = W @ c1_W1  (128x128 @ 128x32) ----------------
__global__ __launch_bounds__(256) void k_wc(const float* __restrict__ W,
                                            const float* __restrict__ W1,
                                            float* __restrict__ Wc) {
    int idx = blockIdx.x * 256 + threadIdx.x;   // 0..4095
    int i = idx >> 5;   // 0..127
    int j = idx & 31;   // 0..31
    float acc = 0.f;
    for (int k = 0; k < DIM_IN; ++k) acc += W[i * DIM_IN + k] * W1[k * HL + j];
    Wc[i * HL + j] = acc;
}

// ---------------- u = x @ Wc  ([N,128] @ [128,32]), 64 nodes/block ----------------
__global__ __launch_bounds__(256) void k_xproj(const float* __restrict__ x,
                                               const float* __restrict__ Wc,
                                               float* __restrict__ u) {
    __shared__ float xs[64][132];     // padded: row stride 132 -> bank shift 4
    __shared__ float Ws[DIM_IN * HL]; // 16 KB
    int t = threadIdx.x;
    int base = blockIdx.x * 64;
    for (int i = t; i < DIM_IN * HL / 4; i += 256)
        ((float4*)Ws)[i] = ((const float4*)Wc)[i];
    for (int i = t; i < 64 * 32; i += 256) {     // 2048 float4s
        int r = i >> 5, c4 = i & 31;
        float4 val;
        if (base + r < N_NODES) val = ((const float4*)x)[(size_t)(base + r) * 32 + c4];
        else val = make_float4(0.f, 0.f, 0.f, 0.f);
        *(float4*)&xs[r][c4 * 4] = val;
    }
    __syncthreads();
    int mg = t >> 3;      // 0..31 -> nodes 2mg, 2mg+1
    int cg = t & 7;       // cols cg*4..+3
    int n0 = mg * 2;
    float4 a0 = make_float4(0.f, 0.f, 0.f, 0.f);
    float4 a1 = make_float4(0.f, 0.f, 0.f, 0.f);
    for (int k = 0; k < DIM_IN; ++k) {
        float x0 = xs[n0][k], x1 = xs[n0 + 1][k];
        float4 b = ((float4*)Ws)[k * 8 + cg];
        a0.x += x0 * b.x; a0.y += x0 * b.y; a0.z += x0 * b.z; a0.w += x0 * b.w;
        a1.x += x1 * b.x; a1.y += x1 * b.y; a1.z += x1 * b.z; a1.w += x1 * b.w;
    }
    int node = base + n0;
    if (node < N_NODES)     ((float4*)u)[(size_t)node * 8 + cg] = a0;
    if (node + 1 < N_NODES) ((float4*)u)[(size_t)(node + 1) * 8 + cg] = a1;
}

// ---- pass 1: per-block fine hist (LDS) -> coarse count matrix + global fine hist ----
__global__ __launch_bounds__(256) void k_hist(const int* __restrict__ dst,
                                              int* __restrict__ cnt_c,
                                              int* __restrict__ bhist) {
    __shared__ int bins[NBUCKET];
    int t = threadIdx.x, blk = blockIdx.x;
    for (int i = t; i < NBUCKET; i += 256) bins[i] = 0;
    __syncthreads();
    int e0 = blk * TILEA, e1 = e0 + TILEA;
    for (int e = e0 + t; e < e1; e += 256) atomicAdd(&bins[dst[e] >> 6], 1);
    __syncthreads();
    if (t < NC) {
        int f0 = t << 3;
        int f1 = f0 + 8; if (f1 > NBUCKET) f1 = NBUCKET;
        int s = 0;
        for (int f = f0; f < f1; ++f) s += bins[f];
        cnt_c[t * NBLKA + blk] = s;
    }
    for (int i = t; i < NBUCKET; i += 256) {
        int v = bins[i];
        if (v) atomicAdd(&bhist[i], v);
    }
}

// ---------------- generic scan pieces ----------------
__global__ __launch_bounds__(256) void k_scan1(const int* __restrict__ in,
                                               int* __restrict__ outp,
                                               int* __restrict__ bsums, int n) {
    __shared__ int s[256];
    int t = threadIdx.x;
    int i = blockIdx.x * 256 + t;
    int val = (i < n) ? in[i] : 0;
    s[t] = val;
    __syncthreads();
    for (int off = 1; off < 256; off <<= 1) {
        int a = 0;
        if (t >= off) a = s[t - off];
        __syncthreads();
        s[t] += a;
        __syncthreads();
    }
    if (i < n) outp[i] = s[t] - val;   // exclusive within block
    if (t == 255) bsums[blockIdx.x] = s[255];
}

__global__ __launch_bounds__(512) void k_scan2(const int* __restrict__ bsums,
                                               int* __restrict__ boffs, int nb) {
    __shared__ int s[512];
    int t = threadIdx.x;
    int val = (t < nb) ? bsums[t] : 0;
    s[t] = val;
    __syncthreads();
    for (int off = 1; off < 512; off <<= 1) {
        int a = 0;
        if (t >= off) a = s[t - off];
        __syncthreads();
        s[t] += a;
        __syncthreads();
    }
    if (t < nb) boffs[t] = s[t] - val;
}

__global__ void k_scan3(int* __restrict__ arr, const int* __restrict__ boffs,
                        int n, int total, int write_total) {
    int i = blockIdx.x * 256 + threadIdx.x;
    if (i < n) arr[i] += boffs[i >> 8];
    if (write_total && i == 0) arr[n] = total;
}

// ---- pass 2: deterministic coarse scatter; per-(block,bucket) runs ~= 64 B ----
__global__ __launch_bounds__(256) void k_scatA(const int* __restrict__ src,
                                               const int* __restrict__ dst,
                                               const int* __restrict__ cnt_c,
                                               unsigned int* __restrict__ pairs1) {
    __shared__ int cur[NC];
    int t = threadIdx.x, blk = blockIdx.x;
    if (t < NC) cur[t] = cnt_c[t * NBLKA + blk];
    __syncthreads();
    int e0 = blk * TILEA, e1 = e0 + TILEA;
    for (int e = e0 + t; e < e1; e += 256) {
        int d = dst[e];
        int p = atomicAdd(&cur[d >> 9], 1);
        pairs1[p] = ((unsigned int)src[e] << 9) | (unsigned int)(d & 511);
    }
}

// ---- pass 3: fine filter; each fine bucket writes its OWN contiguous range ----
// XCD-chunked block swizzle: a coarse bucket's 8 children run on one XCD -> L2 reuse.
__global__ __launch_bounds__(256) void k_scatF(const unsigned int* __restrict__ pairs1,
                                               const int* __restrict__ gbase,
                                               unsigned int* __restrict__ pairs2) {
    int b = (blockIdx.x & 7) * NC + (blockIdx.x >> 3);
    if (b >= NBUCKET) return;
    int c = b >> 3, sub = b & 7;
    int f0 = c << 3;
    int f1 = f0 + 8; if (f1 > NBUCKET) f1 = NBUCKET;
    int cb = gbase[f0], ce = gbase[f1];
    __shared__ int cur;
    int t = threadIdx.x;
    if (t == 0) cur = gbase[b];
    __syncthreads();
    int lane = t & 63;
    for (int s = cb; s < ce; s += 256) {
        int i = s + t;
        bool m = false;
        unsigned int v = 0;
        if (i < ce) {
            v = pairs1[i];
            m = (((v >> 6) & 7u) == (unsigned int)sub);
        }
        unsigned long long mk = __ballot(m);
        int cnt = __popcll(mk);
        if (cnt) {
            int pre = __popcll(mk & ((1ull << lane) - 1ull));
            int base = 0;
            if (lane == 0) base = atomicAdd(&cur, cnt);
            base = __shfl(base, 0, 64);
            if (m) pairs2[base + pre] = ((v >> 9) << 6) | (v & 63u);
        }
    }
}

// ---- pass 4: per-bucket node ordering (row_ptr + srcs), 8 KB windows ----
__global__ __launch_bounds__(256) void k_scatB(const unsigned int* __restrict__ pairs2,
                                               const int* __restrict__ gbase,
                                               int* __restrict__ row_ptr,
                                               int* __restrict__ srcs) {
    __shared__ int bins[64];
    __shared__ int cur[64];
    int t = threadIdx.x, b = blockIdx.x;
    int base = gbase[b], end = gbase[b + 1];
    if (t < 64) bins[t] = 0;
    __syncthreads();
    for (int i = base + t; i < end; i += 256) atomicAdd(&bins[pairs2[i] & 63u], 1);
    __syncthreads();
    if (t < 64) {                       // wave-0 exclusive scan of 64 bins
        int v = bins[t];
        int inc = v;
        for (int off = 1; off < 64; off <<= 1) {
            int o = __shfl_up(inc, off, 64);
            if (t >= off) inc += o;
        }
        int pos = base + inc - v;
        cur[t] = pos;
        int node = (b << 6) + t;
        if (node < N_NODES) row_ptr[node] = pos;
    }
    if (b == NBUCKET - 1 && t == 0) row_ptr[N_NODES] = N_EDGES;
    __syncthreads();
    for (int i = base + t; i < end; i += 256) {
        unsigned int v = pairs2[i];
        int p = atomicAdd(&cur[v & 63u], 1);
        srcs[p] = (int)(v >> 6);
    }
}

// ---- fused conv: compact-u gather + BN + ReLU + @W2 + b2 + ReLU -> hcat slice ----
// Also emits u_next = h @ W1n (pre-projection for the NEXT conv) when W1n != nullptr.
__global__ __launch_bounds__(256) void k_conv(const float* __restrict__ u,
                                              const int* __restrict__ row_ptr,
                                              const int* __restrict__ srcs,
                                              const float* __restrict__ b1,
                                              const float* __restrict__ g,
                                              const float* __restrict__ be,
                                              const float* __restrict__ m,
                                              const float* __restrict__ v,
                                              const float* __restrict__ W2,
                                              const float* __restrict__ b2,
                                              const float* __restrict__ W1n,
                                              float* __restrict__ hout,   // hcat + col_off
                                              float* __restrict__ unext) {
    __shared__ float W2s[HL * HL];
    __shared__ float W1ns[HL * HL];
    __shared__ float ts[8][HL + 1];
    __shared__ float hs[8][HL + 1];
    int t = threadIdx.x;
    bool hasN = (W1n != nullptr);
    for (int i = t; i < HL * HL; i += 256) {
        W2s[i] = W2[i];
        if (hasN) W1ns[i] = W1n[i];
    }
    int slot = t >> 5, d = t & 31;
    int node = blockIdx.x * 8 + slot;          // 12500*8 == N_NODES exactly
    float A = u[(size_t)node * HL + d];
    int e0 = row_ptr[node], e1 = row_ptr[node + 1];
    for (int base = e0; base < e1; base += 32) {
        int p = base + d;
        int idx = srcs[p < e1 ? p : e1 - 1];
        int cnt = e1 - base; if (cnt > 32) cnt = 32;
        float a0 = 0.f, a1 = 0.f, a2 = 0.f, a3 = 0.f;
        int j = 0;
        for (; j + 4 <= cnt; j += 4) {
            int s0 = __shfl(idx, j + 0, 32);
            int s1 = __shfl(idx, j + 1, 32);
            int s2 = __shfl(idx, j + 2, 32);
            int s3 = __shfl(idx, j + 3, 32);
            a0 += u[(size_t)s0 * HL + d];
            a1 += u[(size_t)s1 * HL + d];
            a2 += u[(size_t)s2 * HL + d];
            a3 += u[(size_t)s3 * HL + d];
        }
        for (; j < cnt; ++j) a0 += u[(size_t)__shfl(idx, j, 32) * HL + d];
        A += (a0 + a1) + (a2 + a3);
    }
    // folded BN affine on (A + b1)
    float s = g[d] * rsqrtf(v[d] + BN_EPS);
    float beta = (b1[d] - m[d]) * s + be[d];
    ts[slot][d] = fmaxf(A * s + beta, 0.f);
    __syncthreads();
    float h = b2[d];
    #pragma unroll
    for (int k = 0; k < HL; ++k) h += ts[slot][k] * W2s[k * HL + d];
    h = fmaxf(h, 0.f);
    hout[(size_t)node * DIM_IN + d] = h;
    if (hasN) {
        hs[slot][d] = h;
        __syncthreads();
        float un = 0.f;
        #pragma unroll
        for (int k = 0; k < HL; ++k) un += hs[slot][k] * W1ns[k * HL + d];
        unext[(size_t)node * HL + d] = un;
    }
}

// ------- final: lin1 + ReLU + lin2 + log_softmax, 32 nodes/block, 4x4 acc -------
__global__ __launch_bounds__(256, 4) void k_final(const float* __restrict__ hcat,
                                                  const float* __restrict__ W1,
                                                  const float* __restrict__ b1,
                                                  const float* __restrict__ W2,
                                                  const float* __restrict__ b2,
                                                  float* __restrict__ out) {
    __shared__ float sh_h[32][132];   // row stride 132 -> bank shift 4
    __shared__ float shW[5120];       // W1 32-row chunk (4096 floats) / W2 full (5120)
    int t = threadIdx.x;
    int base = blockIdx.x * 32;       // 3125 * 32 == 100000 exactly
    for (int i = t; i < 1024; i += 256) {
        int r = i >> 5, c4 = i & 31;
        *(float4*)&sh_h[r][c4 * 4] =
            ((const float4*)hcat)[(size_t)(base + r) * 32 + c4];
    }
    int cg = t & 31;          // col group: cols c0..c0+3
    int ng = t >> 5;          // node group: nodes n0..n0+3
    int c0 = cg * 4, n0 = ng * 4;
    float acc[4][4];
    float4 bias = ((const float4*)b1)[cg];
    #pragma unroll
    for (int i = 0; i < 4; ++i) {
        acc[i][0] = bias.x; acc[i][1] = bias.y; acc[i][2] = bias.z; acc[i][3] = bias.w;
    }
    for (int kk = 0; kk < DIM_IN; kk += 32) {
        __syncthreads();
        for (int i = t; i < 1024; i += 256)
            ((float4*)shW)[i] = ((const float4*)W1)[(size_t)(kk + (i >> 5)) * 32 + (i & 31)];
        __syncthreads();
        #pragma unroll 4
        for (int k = 0; k < 32; ++k) {
            float4 b = ((float4*)shW)[k * 32 + cg];
            #pragma unroll
            for (int i = 0; i < 4; ++i) {
                float a = sh_h[n0 + i][kk + k];
                acc[i][0] += a * b.x; acc[i][1] += a * b.y;
                acc[i][2] += a * b.z; acc[i][3] += a * b.w;
            }
        }
    }
    __syncthreads();
    #pragma unroll
    for (int i = 0; i < 4; ++i) {
        float4 vv = make_float4(fmaxf(acc[i][0], 0.f), fmaxf(acc[i][1], 0.f),
                                fmaxf(acc[i][2], 0.f), fmaxf(acc[i][3], 0.f));
        *(float4*)&sh_h[n0 + i][c0] = vv;
    }
    for (int i = t; i < 1280; i += 256) ((float4*)shW)[i] = ((const float4*)W2)[i];
    __syncthreads();
    int nn = t >> 3;
    int c2 = (t & 7) * 5;
    float acc2[5];
    #pragma unroll
    for (int j = 0; j < 5; ++j) acc2[j] = b2[c2 + j];
    #pragma unroll 4
    for (int k = 0; k < DIM_IN; ++k) {
        float a = sh_h[nn][k];
        #pragma unroll
        for (int j = 0; j < 5; ++j) acc2[j] += a * shW[k * 40 + c2 + j];
    }
    float mx = acc2[0];
    #pragma unroll
    for (int j = 1; j < 5; ++j) mx = fmaxf(mx, acc2[j]);
    for (int off = 1; off < 8; off <<= 1) mx = fmaxf(mx, __shfl_xor(mx, off, 8));
    float sm = 0.f;
    #pragma unroll
    for (int j = 0; j < 5; ++j) sm += expf(acc2[j] - mx);
    for (int off = 1; off < 8; off <<= 1) sm += __shfl_xor(sm, off, 8);
    float lz = mx + logf(sm);
    int node = base + nn;
    #pragma unroll
    for (int j = 0; j < 5; ++j) {
        float o = acc2[j];
        out[(size_t)node * DIM_OUT + c2 + j] = o;
        out[(size_t)N_NODES * DIM_OUT + (size_t)node * DIM_OUT + c2 + j] = o - lz;
    }
}

extern "C" void kernel_launch(void* const* d_in, const int* in_sizes, int n_in,
                              void* d_out, int out_size, void* d_ws, size_t ws_size,
                              hipStream_t stream) {
    const float* x      = (const float*)d_in[0];
    const int*   ei     = (const int*)d_in[1];
    const float* W      = (const float*)d_in[2];
    const float* c1_W1  = (const float*)d_in[3];
    const float* c1_b1  = (const float*)d_in[4];
    const float* c1_g   = (const float*)d_in[5];
    const float* c1_be  = (const float*)d_in[6];
    const float* c1_m   = (const float*)d_in[7];
    const float* c1_v   = (const float*)d_in[8];
    const float* c1_W2  = (const float*)d_in[9];
    const float* c1_b2  = (const float*)d_in[10];
    const float* cW1    = (const float*)d_in[11];
    const float* cb1    = (const float*)d_in[12];
    const float* cg     = (const float*)d_in[13];
    const float* cbe    = (const float*)d_in[14];
    const float* cm     = (const float*)d_in[15];
    const float* cv     = (const float*)d_in[16];
    const float* cW2    = (const float*)d_in[17];
    const float* cb2    = (const float*)d_in[18];
    const float* lin1_W = (const float*)d_in[19];
    const float* lin1_b = (const float*)d_in[20];
    const float* lin2_W = (const float*)d_in[21];
    const float* lin2_b = (const float*)d_in[22];

    const int* esrc = ei;
    const int* edst = ei + N_EDGES;

    // workspace carve (~78.1 MB)
    float* uA      = (float*)d_ws;                        // N*32 floats
    float* hcat    = uA + (size_t)N_NODES * HL;           // N*128 floats
    unsigned int* pairs1 = (unsigned int*)hcat;           // E (alias, pre-conv)
    unsigned int* pairs2 = pairs1 + N_EDGES;              // E (alias, pre-conv)
    float* Wc      = hcat + (size_t)N_NODES * DIM_IN;     // 128*32
    int*   row_ptr = (int*)(Wc + DIM_IN * HL);            // N+1
    int*   srcs    = row_ptr + (N_NODES + 1);             // E
    int*   cnt_c   = srcs + N_EDGES;                      // M_CNT
    int*   bhist   = cnt_c + M_CNT;                       // NBUCKET
    int*   gbase   = bhist + NBUCKET;                     // NBUCKET+1
    int*   bsA1    = gbase + (NBUCKET + 1);               // 784
    int*   bsA2    = bsA1 + 784;                          // 4
    int*   boA2    = bsA2 + 4;                            // 4
    int*   bsB     = boA2 + 4;                            // 7
    int*   boB     = bsB + 7;                             // 7

    float* uB = (float*)d_out;   // scratch until k_final rewrites d_out

    const int NB_CONV = N_NODES / 8;             // 12500 (exact)
    const int NB_T64  = (N_NODES + 63) / 64;     // 1563

    hipMemsetAsync(bhist, 0, NBUCKET * sizeof(int), stream);
    k_wc<<<16, 256, 0, stream>>>(W, c1_W1, Wc);
    k_xproj<<<NB_T64, 256, 0, stream>>>(x, Wc, uA);

    // hist (fine LDS -> coarse matrix + global fine)
    k_hist<<<NBLKA, 256, 0, stream>>>(edst, cnt_c, bhist);
    // 3-level scan of coarse count matrix (200704 entries, bucket-major)
    k_scan1<<<M_CNT / 256, 256, 0, stream>>>(cnt_c, cnt_c, bsA1, M_CNT);
    k_scan1<<<4, 256, 0, stream>>>(bsA1, bsA1, bsA2, 784);
    k_scan2<<<1, 512, 0, stream>>>(bsA2, boA2, 4);
    k_scan3<<<4, 256, 0, stream>>>(bsA1, boA2, 784, 0, 0);
    k_scan3<<<M_CNT / 256, 256, 0, stream>>>(cnt_c, bsA1, M_CNT, 0, 0);
    // fine-bucket bases
    k_scan1<<<7, 256, 0, stream>>>(bhist, gbase, bsB, NBUCKET);
    k_scan2<<<1, 512, 0, stream>>>(bsB, boB, 7);
    k_scan3<<<7, 256, 0, stream>>>(gbase, boB, NBUCKET, N_EDGES, 1);
    // scatter: coarse (line-sized runs) -> fine (single-writer ranges) -> node order
    k_scatA<<<NBLKA, 256, 0, stream>>>(esrc, edst, cnt_c, pairs1);
    k_scatF<<<NC * 8, 256, 0, stream>>>(pairs1, gbase, pairs2);
    k_scatB<<<NBUCKET, 256, 0, stream>>>(pairs2, gbase, row_ptr, srcs);

    // conv1..4: gather compact u, emit next conv's pre-projected u (ping-pong uA/uB)
    k_conv<<<NB_CONV, 256, 0, stream>>>(uA, row_ptr, srcs, c1_b1, c1_g, c1_be, c1_m,
                                        c1_v, c1_W2, c1_b2, cW1, hcat, uB);
    k_conv<<<NB_CONV, 256, 0, stream>>>(uB, row_ptr, srcs, cb1, cg, cbe, cm, cv,
                                        cW2, cb2, cW1 + HL * HL, hcat + HL, uA);
    k_conv<<<NB_CONV, 256, 0, stream>>>(uA, row_ptr, srcs, cb1 + HL, cg + HL, cbe + HL,
                                        cm + HL, cv + HL, cW2 + HL * HL, cb2 + HL,
                                        cW1 + 2 * HL * HL, hcat + 2 * HL, uB);
    k_conv<<<NB_CONV, 256, 0, stream>>>(uB, row_ptr, srcs, cb1 + 2 * HL, cg + 2 * HL,
                                        cbe + 2 * HL, cm + 2 * HL, cv + 2 * HL,
                                        cW2 + 2 * HL * HL, cb2 + 2 * HL,
                                        nullptr, hcat + 3 * HL, nullptr);

    k_final<<<N_NODES / 32, 256, 0, stream>>>(hcat, lin1_W, lin1_b, lin2_W, lin2_b,
                                              (float*)d_out);
}